// Round 16
// baseline (458.659 us; speedup 1.0000x reference)
//
#include <hip/hip_runtime.h>
#include <math.h>

// N=100000 nodes, E=6400000 edges, avg degree 64.
// out[n] = [cos(th_n), sin(th_n), w_n],  w_n = S_y / max(||S||, eps),
//   S_x = cos(th)*C + sin(th)*S,  S_y = cos(th)*S - sin(th)*C,
//   C_n = sum_{e:dst=n} cos(x[src_e]),  S_n = sum_{e:dst=n} sin(x[src_e]).
//
// Model (R1-R15): global fp atomics write through to HBM (634us, R1/R8).
// LDS-partition rescan: ~0.57-0.7 cyc/edge-visit/CU. NOT bandwidth-bound
// (VALU 20%, HBM 7%, L1/L2 streams <=25% of ceilings at 32 waves/CU) and
// NOT wave-starved (R15: 24->32 waves = -3%). Cost scales with per-visit
// instruction count: MLP x2 = -13% (R14); payload VALU -70% = 0 (R11).
// R12/R13: dynamic LDS >50KB kills residency or graph replay.
// R16: (a) edst-only unconditional stream; esrc loaded MASKED on hit
// lanes (1/16) in its own pass so loads stay independent -> halves index
// bytes and removes 2 big loads + addr VALU per 8 edges. (b) reduce fused
// into scatter via per-partition done counters (device-scope atomicAdd +
// threadfence, zeroed in prep): last block of each partition reduces its
// R nodes. 2 kernels total.
// Fixed-point u64: addend=(1<<52)|(sin+32768)<<26|(cos+32768), scale
// 2^15; per-node degree <150 => fields never carry; decode at reduce.

#define EPS 1e-12f
#define NPART 16
#define RMAX 6250        // u64[6250] = 50KB static LDS; 2 blk/CU @ BLK=1024
#define BLK 1024

static __device__ __forceinline__ unsigned long long pack_cs(float xv) {
    float sn, cs;
    __sincosf(xv, &sn, &cs);
    const int ci = __float2int_rn(cs * 32768.0f);   // [-32768, 32768]
    const int si = __float2int_rn(sn * 32768.0f);
    return (1ull << 52)
         | ((unsigned long long)(unsigned)(si + 32768) << 26)
         | (unsigned long long)(unsigned)(ci + 32768);
}

// ---------------- prep: packed-addend table + zero done counters ----------
__global__ __launch_bounds__(256) void prep_pack_kernel(
        const float* __restrict__ x,
        unsigned long long* __restrict__ pu,
        int* __restrict__ done, int N) {
    int i = blockIdx.x * blockDim.x + threadIdx.x;
    if (blockIdx.x == 0 && threadIdx.x < NPART) done[threadIdx.x] = 0;
    if (i < N) pu[i] = pack_cs(x[i]);
}

// ---------------- scatter + fused per-partition reduce ----------------
__global__ __launch_bounds__(BLK, 2) void scatter_kernel(
        const unsigned long long* __restrict__ pu,
        const float* __restrict__ theta,
        const int* __restrict__ esrc,
        const int* __restrict__ edst,
        unsigned long long* __restrict__ partials,   // [NPART*nslice][R]
        int* __restrict__ done,                      // [NPART]
        float* __restrict__ out,
        int E, int N, int R, int nslice) {
    __shared__ unsigned long long lacc[RMAX];
    __shared__ int last_flag;
    const int p = blockIdx.x / nslice;
    const int s = blockIdx.x % nslice;   // nslice%8==0 -> XCD = blk%8 = s%8
    const int pBeg = p * R;

    for (int k = threadIdx.x; k < R; k += BLK) lacc[k] = 0ull;
    __syncthreads();

    const int per = (((E + nslice - 1) / nslice) + 7) & ~7;
    const int beg = s * per;
    const int end = min(beg + per, E);
    const int end8 = beg + (max(end - beg, 0) & ~7);

    for (int i = beg + threadIdx.x * 8; i < end8; i += BLK * 8) {
        // edst only: 2 independent 16B loads (the sole unconditional stream)
        const int4 da = *(const int4*)&edst[i];
        const int4 db = *(const int4*)&edst[i + 4];
        const unsigned dl0 = (unsigned)(da.x - pBeg);
        const unsigned dl1 = (unsigned)(da.y - pBeg);
        const unsigned dl2 = (unsigned)(da.z - pBeg);
        const unsigned dl3 = (unsigned)(da.w - pBeg);
        const unsigned dl4 = (unsigned)(db.x - pBeg);
        const unsigned dl5 = (unsigned)(db.y - pBeg);
        const unsigned dl6 = (unsigned)(db.z - pBeg);
        const unsigned dl7 = (unsigned)(db.w - pBeg);
        const bool h0 = dl0 < (unsigned)R, h1 = dl1 < (unsigned)R;
        const bool h2 = dl2 < (unsigned)R, h3 = dl3 < (unsigned)R;
        const bool h4 = dl4 < (unsigned)R, h5 = dl5 < (unsigned)R;
        const bool h6 = dl6 < (unsigned)R, h7 = dl7 < (unsigned)R;
        // pass A: masked esrc loads (hit lanes only), mutually independent
        int s0 = 0, s1 = 0, s2 = 0, s3 = 0, s4 = 0, s5 = 0, s6 = 0, s7 = 0;
        if (h0) s0 = esrc[i + 0];
        if (h1) s1 = esrc[i + 1];
        if (h2) s2 = esrc[i + 2];
        if (h3) s3 = esrc[i + 3];
        if (h4) s4 = esrc[i + 4];
        if (h5) s5 = esrc[i + 5];
        if (h6) s6 = esrc[i + 6];
        if (h7) s7 = esrc[i + 7];
        // pass B: masked pu gathers, mutually independent
        unsigned long long v0 = 0, v1 = 0, v2 = 0, v3 = 0;
        unsigned long long v4 = 0, v5 = 0, v6 = 0, v7 = 0;
        if (h0) v0 = pu[s0];
        if (h1) v1 = pu[s1];
        if (h2) v2 = pu[s2];
        if (h3) v3 = pu[s3];
        if (h4) v4 = pu[s4];
        if (h5) v5 = pu[s5];
        if (h6) v6 = pu[s6];
        if (h7) v7 = pu[s7];
        // pass C: masked LDS atomics
        if (h0) atomicAdd(&lacc[dl0], v0);
        if (h1) atomicAdd(&lacc[dl1], v1);
        if (h2) atomicAdd(&lacc[dl2], v2);
        if (h3) atomicAdd(&lacc[dl3], v3);
        if (h4) atomicAdd(&lacc[dl4], v4);
        if (h5) atomicAdd(&lacc[dl5], v5);
        if (h6) atomicAdd(&lacc[dl6], v6);
        if (h7) atomicAdd(&lacc[dl7], v7);
    }
    for (int i = end8 + threadIdx.x; i < end; i += BLK) {
        const unsigned dl = (unsigned)(edst[i] - pBeg);
        if (dl < (unsigned)R) atomicAdd(&lacc[dl], pu[esrc[i]]);
    }

    __syncthreads();
    unsigned long long* dst = partials + (size_t)blockIdx.x * R;
    for (int k = threadIdx.x; k < R; k += BLK) dst[k] = lacc[k];

    // publish this block's partials, then let the LAST block of the
    // partition do the reduce (threadFenceReduction pattern)
    __threadfence();
    __syncthreads();
    if (threadIdx.x == 0) {
        const int old = atomicAdd(&done[p], 1);
        last_flag = (old == nslice - 1) ? 1 : 0;
    }
    __syncthreads();
    if (!last_flag) return;
    __threadfence();   // acquire: see all partitions' partials

    const unsigned long long* basep = partials + (size_t)p * nslice * R;
    for (int j = threadIdx.x; j < R; j += BLK) {
        const int n = pBeg + j;
        if (n >= N) break;
        unsigned long long t = 0ull;
        #pragma unroll 8
        for (int ss = 0; ss < nslice; ++ss) t += basep[(size_t)ss * R + j];
        const long long k  = (long long)(t >> 52);
        const long long cf = (long long)(t & 0x3FFFFFFull);
        const long long sf = (long long)((t >> 26) & 0x3FFFFFFull);
        const float C  = (float)(cf - k * 32768) * (1.0f / 32768.0f);
        const float Sv = (float)(sf - k * 32768) * (1.0f / 32768.0f);
        float sn, cs;
        __sincosf(theta[n], &sn, &cs);
        const float nrm = fmaxf(sqrtf(C * C + Sv * Sv), EPS);
        out[3 * n + 0] = cs;
        out[3 * n + 1] = sn;
        out[3 * n + 2] = (cs * Sv - sn * C) / nrm;
    }
}

// ---------------- R8 fallback: global native atomics ----------------
__global__ __launch_bounds__(256) void prep_acc_kernel(float2* __restrict__ acc, int N) {
    int i = blockIdx.x * blockDim.x + threadIdx.x;
    if (i < N) acc[i] = make_float2(0.0f, 0.0f);
}

__global__ __launch_bounds__(256) void edge_scatter_sincos_kernel(
        const int* __restrict__ esrc,
        const int* __restrict__ edst,
        const float* __restrict__ x,
        float2* __restrict__ acc, int E) {
    const int i = (blockIdx.x * 256 + threadIdx.x) * 4;
    float* accf = (float*)acc;
    for (int k = i; k < min(i + 4, E); ++k) {
        float sn, cs;
        __sincosf(x[esrc[k]], &sn, &cs);
        const int d = edst[k];
        unsafeAtomicAdd(&accf[2 * d],     cs);
        unsafeAtomicAdd(&accf[2 * d + 1], sn);
    }
}

__global__ __launch_bounds__(256) void node_kernel(
        const float* __restrict__ theta,
        const float2* __restrict__ acc,
        float* __restrict__ out, int N) {
    int n = blockIdx.x * blockDim.x + threadIdx.x;
    if (n >= N) return;
    float sn, cs;
    __sincosf(theta[n], &sn, &cs);
    const float2 a = acc[n];
    const float nrm = fmaxf(sqrtf(a.x * a.x + a.y * a.y), EPS);
    out[3 * n + 0] = cs;
    out[3 * n + 1] = sn;
    out[3 * n + 2] = (cs * a.y - sn * a.x) / nrm;
}

extern "C" void kernel_launch(void* const* d_in, const int* in_sizes, int n_in,
                              void* d_out, int out_size, void* d_ws, size_t ws_size,
                              hipStream_t stream) {
    const float* x     = (const float*)d_in[0];
    const float* theta = (const float*)d_in[1];
    const int*   esrc  = (const int*)d_in[2];
    const int*   edst  = (const int*)d_in[3];
    float*       out   = (float*)d_out;

    const int N = in_sizes[0];
    const int E = in_sizes[2];
    const size_t pu_bytes   = (size_t)N * sizeof(unsigned long long);
    const size_t done_bytes = 256;

    // ---------- main path: NPART=16, static 50KB, fused reduce ----------
    {
        const int R = (N + NPART - 1) / NPART;
        if (R <= RMAX) {
            for (int nslice : {32, 16, 8}) {
                const size_t part_bytes =
                    (size_t)NPART * nslice * R * sizeof(unsigned long long);
                if (ws_size >= part_bytes + pu_bytes + done_bytes) {
                    unsigned long long* partials = (unsigned long long*)d_ws;
                    unsigned long long* pu =
                        (unsigned long long*)((char*)d_ws + part_bytes);
                    int* done = (int*)((char*)d_ws + part_bytes + pu_bytes);
                    prep_pack_kernel<<<(N + 255) / 256, 256, 0, stream>>>(
                        x, pu, done, N);
                    scatter_kernel<<<NPART * nslice, BLK, 0, stream>>>(
                        pu, theta, esrc, edst, partials, done, out, E, N, R, nslice);
                    return;
                }
            }
        }
    }

    // ---------- R8 fallback: global native atomics ----------
    float2* acc = (float2*)d_ws;   // 800KB
    prep_acc_kernel<<<(N + 255) / 256, 256, 0, stream>>>(acc, N);
    edge_scatter_sincos_kernel<<<(E + 1023) / 1024, 256, 0, stream>>>(esrc, edst, x, acc, E);
    node_kernel<<<(N + 255) / 256, 256, 0, stream>>>(theta, acc, out, N);
}

// Round 17
// 451.574 us; speedup vs baseline: 1.0157x; 1.0157x over previous
//
#include <hip/hip_runtime.h>
#include <math.h>

// N=100000 nodes, E=6400000 edges, avg degree 64.
// out[n] = [cos(th_n), sin(th_n), w_n],  w_n = S_y / max(||S||, eps),
//   S_x = cos(th)*C + sin(th)*S,  S_y = cos(th)*S - sin(th)*C,
//   C_n = sum_{e:dst=n} cos(x[src_e]),  S_n = sum_{e:dst=n} sin(x[src_e]).
//
// Model (R1-R16): global fp atomics write through to HBM (634us, R1/R8).
// LDS-partition rescan floor ~0.57 cyc/edge-visit/CU: insensitive to
// payload VALU (R11), atomic width (R10), occupancy 24->32 waves (R15:
// -3%); responsive to per-wave MLP (R14: -13%). R16's exec-masked scalar
// esrc loads were a 4x REGRESSION (8 sparse dword loads w/ exec dance
// replaced 2 coalesced 16B loads; FETCH +46%, VALUBusy 5.6%): the dense
// unconditional index stream is load-bearing. R12/R13: >50KB LDS kills
// residency (dynamic granularity) or graph replay (attr ignored).
// R17 = R15 loop VERBATIM (unconditional edst+esrc int4 x2, masked pu
// gathers, 1 ds_add_u64/edge, 50KB static, BLK=1024, nslice=32 -> 32
// waves/CU) + R16's fused reduce tail (threadfence + done-counter; the
// last block per partition reduces + writes epilogue). 2 kernels total.
// Fixed-point u64: addend=(1<<52)|(sin+32768)<<26|(cos+32768), scale
// 2^15; per-node degree <150 => fields never carry; decode at reduce.

#define EPS 1e-12f
#define NPART 16
#define RMAX 6250        // u64[6250] = 50KB static LDS; 2 blk/CU @ BLK=1024
#define BLK 1024

static __device__ __forceinline__ unsigned long long pack_cs(float xv) {
    float sn, cs;
    __sincosf(xv, &sn, &cs);
    const int ci = __float2int_rn(cs * 32768.0f);   // [-32768, 32768]
    const int si = __float2int_rn(sn * 32768.0f);
    return (1ull << 52)
         | ((unsigned long long)(unsigned)(si + 32768) << 26)
         | (unsigned long long)(unsigned)(ci + 32768);
}

// ---------------- prep: packed-addend table + zero done counters ----------
__global__ __launch_bounds__(256) void prep_pack_kernel(
        const float* __restrict__ x,
        unsigned long long* __restrict__ pu,
        int* __restrict__ done, int N) {
    int i = blockIdx.x * blockDim.x + threadIdx.x;
    if (blockIdx.x == 0 && threadIdx.x < NPART) done[threadIdx.x] = 0;
    if (i < N) pu[i] = pack_cs(x[i]);
}

// ---------------- scatter (R15 loop) + fused per-partition reduce ---------
__global__ __launch_bounds__(BLK, 2) void scatter_kernel(
        const unsigned long long* __restrict__ pu,
        const float* __restrict__ theta,
        const int* __restrict__ esrc,
        const int* __restrict__ edst,
        unsigned long long* __restrict__ partials,   // [NPART*nslice][R]
        int* __restrict__ done,                      // [NPART]
        float* __restrict__ out,
        int E, int N, int R, int nslice) {
    __shared__ unsigned long long lacc[RMAX];
    __shared__ int last_flag;
    const int p = blockIdx.x / nslice;
    const int s = blockIdx.x % nslice;   // nslice%8==0 -> XCD = blk%8 = s%8
    const int pBeg = p * R;

    for (int k = threadIdx.x; k < R; k += BLK) lacc[k] = 0ull;
    __syncthreads();

    const int per = (((E + nslice - 1) / nslice) + 7) & ~7;
    const int beg = s * per;
    const int end = min(beg + per, E);
    const int end8 = beg + (max(end - beg, 0) & ~7);

    for (int i = beg + threadIdx.x * 8; i < end8; i += BLK * 8) {
        // 4 independent UNCONDITIONAL 16B index loads (R16 lesson: the
        // dense coalesced stream beats sparse masked loads)
        const int4 da = *(const int4*)&edst[i];
        const int4 db = *(const int4*)&edst[i + 4];
        const int4 sa = *(const int4*)&esrc[i];
        const int4 sb = *(const int4*)&esrc[i + 4];
        const unsigned dl0 = (unsigned)(da.x - pBeg);
        const unsigned dl1 = (unsigned)(da.y - pBeg);
        const unsigned dl2 = (unsigned)(da.z - pBeg);
        const unsigned dl3 = (unsigned)(da.w - pBeg);
        const unsigned dl4 = (unsigned)(db.x - pBeg);
        const unsigned dl5 = (unsigned)(db.y - pBeg);
        const unsigned dl6 = (unsigned)(db.z - pBeg);
        const unsigned dl7 = (unsigned)(db.w - pBeg);
        const bool h0 = dl0 < (unsigned)R, h1 = dl1 < (unsigned)R;
        const bool h2 = dl2 < (unsigned)R, h3 = dl3 < (unsigned)R;
        const bool h4 = dl4 < (unsigned)R, h5 = dl5 < (unsigned)R;
        const bool h6 = dl6 < (unsigned)R, h7 = dl7 < (unsigned)R;
        // 8 masked 8B gathers from the L2-resident pu table, all in
        // flight before the first atomic
        unsigned long long v0 = 0, v1 = 0, v2 = 0, v3 = 0;
        unsigned long long v4 = 0, v5 = 0, v6 = 0, v7 = 0;
        if (h0) v0 = pu[sa.x];
        if (h1) v1 = pu[sa.y];
        if (h2) v2 = pu[sa.z];
        if (h3) v3 = pu[sa.w];
        if (h4) v4 = pu[sb.x];
        if (h5) v5 = pu[sb.y];
        if (h6) v6 = pu[sb.z];
        if (h7) v7 = pu[sb.w];
        if (h0) atomicAdd(&lacc[dl0], v0);
        if (h1) atomicAdd(&lacc[dl1], v1);
        if (h2) atomicAdd(&lacc[dl2], v2);
        if (h3) atomicAdd(&lacc[dl3], v3);
        if (h4) atomicAdd(&lacc[dl4], v4);
        if (h5) atomicAdd(&lacc[dl5], v5);
        if (h6) atomicAdd(&lacc[dl6], v6);
        if (h7) atomicAdd(&lacc[dl7], v7);
    }
    for (int i = end8 + threadIdx.x; i < end; i += BLK) {
        const unsigned dl = (unsigned)(edst[i] - pBeg);
        if (dl < (unsigned)R) atomicAdd(&lacc[dl], pu[esrc[i]]);
    }

    __syncthreads();
    unsigned long long* dst = partials + (size_t)blockIdx.x * R;
    for (int k = threadIdx.x; k < R; k += BLK) dst[k] = lacc[k];

    // threadFenceReduction: last block of the partition reduces it
    __threadfence();
    __syncthreads();
    if (threadIdx.x == 0) {
        const int old = atomicAdd(&done[p], 1);
        last_flag = (old == nslice - 1) ? 1 : 0;
    }
    __syncthreads();
    if (!last_flag) return;
    __threadfence();   // acquire: see all blocks' partials

    const unsigned long long* basep = partials + (size_t)p * nslice * R;
    for (int j = threadIdx.x; j < R; j += BLK) {
        const int n = pBeg + j;
        if (n >= N) break;
        unsigned long long t = 0ull;
        #pragma unroll 8
        for (int ss = 0; ss < nslice; ++ss) t += basep[(size_t)ss * R + j];
        const long long k  = (long long)(t >> 52);
        const long long cf = (long long)(t & 0x3FFFFFFull);
        const long long sf = (long long)((t >> 26) & 0x3FFFFFFull);
        const float C  = (float)(cf - k * 32768) * (1.0f / 32768.0f);
        const float Sv = (float)(sf - k * 32768) * (1.0f / 32768.0f);
        float sn, cs;
        __sincosf(theta[n], &sn, &cs);
        const float nrm = fmaxf(sqrtf(C * C + Sv * Sv), EPS);
        out[3 * n + 0] = cs;
        out[3 * n + 1] = sn;
        out[3 * n + 2] = (cs * Sv - sn * C) / nrm;
    }
}

// ---------------- R8 fallback: global native atomics ----------------
__global__ __launch_bounds__(256) void prep_acc_kernel(float2* __restrict__ acc, int N) {
    int i = blockIdx.x * blockDim.x + threadIdx.x;
    if (i < N) acc[i] = make_float2(0.0f, 0.0f);
}

__global__ __launch_bounds__(256) void edge_scatter_sincos_kernel(
        const int* __restrict__ esrc,
        const int* __restrict__ edst,
        const float* __restrict__ x,
        float2* __restrict__ acc, int E) {
    const int i = (blockIdx.x * 256 + threadIdx.x) * 4;
    float* accf = (float*)acc;
    for (int k = i; k < min(i + 4, E); ++k) {
        float sn, cs;
        __sincosf(x[esrc[k]], &sn, &cs);
        const int d = edst[k];
        unsafeAtomicAdd(&accf[2 * d],     cs);
        unsafeAtomicAdd(&accf[2 * d + 1], sn);
    }
}

__global__ __launch_bounds__(256) void node_kernel(
        const float* __restrict__ theta,
        const float2* __restrict__ acc,
        float* __restrict__ out, int N) {
    int n = blockIdx.x * blockDim.x + threadIdx.x;
    if (n >= N) return;
    float sn, cs;
    __sincosf(theta[n], &sn, &cs);
    const float2 a = acc[n];
    const float nrm = fmaxf(sqrtf(a.x * a.x + a.y * a.y), EPS);
    out[3 * n + 0] = cs;
    out[3 * n + 1] = sn;
    out[3 * n + 2] = (cs * a.y - sn * a.x) / nrm;
}

extern "C" void kernel_launch(void* const* d_in, const int* in_sizes, int n_in,
                              void* d_out, int out_size, void* d_ws, size_t ws_size,
                              hipStream_t stream) {
    const float* x     = (const float*)d_in[0];
    const float* theta = (const float*)d_in[1];
    const int*   esrc  = (const int*)d_in[2];
    const int*   edst  = (const int*)d_in[3];
    float*       out   = (float*)d_out;

    const int N = in_sizes[0];
    const int E = in_sizes[2];
    const size_t pu_bytes   = (size_t)N * sizeof(unsigned long long);
    const size_t done_bytes = 256;

    // ---------- main path: NPART=16, static 50KB, fused reduce ----------
    {
        const int R = (N + NPART - 1) / NPART;
        if (R <= RMAX) {
            for (int nslice : {32, 16, 8}) {
                const size_t part_bytes =
                    (size_t)NPART * nslice * R * sizeof(unsigned long long);
                if (ws_size >= part_bytes + pu_bytes + done_bytes) {
                    unsigned long long* partials = (unsigned long long*)d_ws;
                    unsigned long long* pu =
                        (unsigned long long*)((char*)d_ws + part_bytes);
                    int* done = (int*)((char*)d_ws + part_bytes + pu_bytes);
                    prep_pack_kernel<<<(N + 255) / 256, 256, 0, stream>>>(
                        x, pu, done, N);
                    scatter_kernel<<<NPART * nslice, BLK, 0, stream>>>(
                        pu, theta, esrc, edst, partials, done, out, E, N, R, nslice);
                    return;
                }
            }
        }
    }

    // ---------- R8 fallback: global native atomics ----------
    float2* acc = (float2*)d_ws;   // 800KB
    prep_acc_kernel<<<(N + 255) / 256, 256, 0, stream>>>(acc, N);
    edge_scatter_sincos_kernel<<<(E + 1023) / 1024, 256, 0, stream>>>(esrc, edst, x, acc, E);
    node_kernel<<<(N + 255) / 256, 256, 0, stream>>>(theta, acc, out, N);
}